// Round 2
// baseline (324.244 us; speedup 1.0000x reference)
//
#include <hip/hip_runtime.h>

using f32x4 = __attribute__((ext_vector_type(4))) float;
using s16x8 = __attribute__((ext_vector_type(8))) short;

constexpr int NB   = 16;    // batch
constexpr int CH   = 256;   // channels
constexpr int TT   = 4096;  // time
constexpr int NT   = 64;    // tokens per tile
constexpr int HALO = 8;     // (K-1)*DIL
constexpr int PITCH = 264;  // bf16 elements per LDS row (256 + 8 pad, 16B aligned)
constexpr int XROWS = NT + HALO;  // 72

__device__ __forceinline__ float b2f(ushort u) {
    unsigned v = ((unsigned)u) << 16;
    float f; __builtin_memcpy(&f, &v, 4); return f;
}
__device__ __forceinline__ ushort f2b(float f) {
    unsigned u; __builtin_memcpy(&u, &f, 4);
    u += 0x7FFFu + ((u >> 16) & 1u);   // RNE
    return (ushort)(u >> 16);
}
__device__ __forceinline__ float fast_sigmoid(float x) {
    return __builtin_amdgcn_rcpf(1.f + __expf(-x));
}
__device__ __forceinline__ float fast_tanh(float x) {
    return 2.f * __builtin_amdgcn_rcpf(1.f + __expf(-2.f * x)) - 1.f;
}

// Convert f32 weights to bf16, rearranged:
// W1[m][k]: m<256 filter / m>=256 gate, k = tap*256 + in_ch.
// W2[m][i]: m<256 res / m>=256 skip.
__global__ void prep_w(const float* __restrict__ wf, const float* __restrict__ wg,
                       const float* __restrict__ wr, const float* __restrict__ wsk,
                       ushort* __restrict__ W1, ushort* __restrict__ W2) {
    int idx = blockIdx.x * 256 + threadIdx.x;
    if (idx < 512 * 512) {
        int m = idx >> 9, k = idx & 511, tap = k >> 8, i = k & 255;
        float v = (m < 256) ? wf[((m << 8) + i) * 2 + tap]
                            : wg[(((m - 256) << 8) + i) * 2 + tap];
        W1[idx] = f2b(v);
    } else {
        int j = idx - 512 * 512;
        int m = j >> 8, i = j & 255;
        float v = (m < 256) ? wr[(m << 8) + i] : wsk[((m - 256) << 8) + i];
        W2[j] = f2b(v);
    }
}

__global__ __launch_bounds__(256, 2)
void fused_block(const float* __restrict__ x,
                 const ushort* __restrict__ W1, const ushort* __restrict__ W2,
                 const float* __restrict__ b_filt, const float* __restrict__ b_gate,
                 const float* __restrict__ b_res,  const float* __restrict__ b_skip,
                 float* __restrict__ out) {
    // Single bf16 tile buffer: rows 0..71 hold x[token][channel] (token = t0-8+row);
    // after GEMM1 it is reused: rows 0..63 hold z[token][channel] (token = t0+row).
    __shared__ __align__(16) ushort ldsx[XROWS * PITCH];   // 38016 bytes

    const int tid = threadIdx.x;
    const int tilesPerB = TT / NT;                 // 64
    const int b  = blockIdx.x / tilesPerB;
    const int t0 = (blockIdx.x % tilesPerB) * NT;
    const float* X = x + (size_t)b * CH * TT;
    const int tg0 = t0 - HALO;

    // ---------------- stage x (f32 -> bf16, transposed) into LDS ----------------
    {
        const int tc   = tid & 15;     // token-chunk (4 tokens = 16B f32)
        const int crow = tid >> 4;     // 0..15
        #pragma unroll
        for (int cg = 0; cg < 16; ++cg) {
            int c  = cg * 16 + crow;
            int tg = tg0 + tc * 4;
            f32x4 v = {0.f, 0.f, 0.f, 0.f};
            if (tg >= 0) v = *(const f32x4*)&X[(size_t)c * TT + tg];
            #pragma unroll
            for (int e = 0; e < 4; ++e)
                ldsx[(tc * 4 + e) * PITCH + c] = f2b(v[e]);
        }
        // tail rows 64..71 = tokens t0+56..t0+63 (always in range)
        {
            int c = tid;
            f32x4 v0 = *(const f32x4*)&X[(size_t)c * TT + tg0 + 64];
            f32x4 v1 = *(const f32x4*)&X[(size_t)c * TT + tg0 + 68];
            #pragma unroll
            for (int e = 0; e < 4; ++e) {
                ldsx[(64 + e) * PITCH + c] = f2b(v0[e]);
                ldsx[(68 + e) * PITCH + c] = f2b(v1[e]);
            }
        }
    }
    __syncthreads();

    const int wave = tid >> 6, lane = tid & 63;
    const int l16 = lane & 15, quad = lane >> 4;
    const int cb = wave * 64;   // this wave's 64-channel output stripe

    // ---------------- GEMM1: [512x512] @ [512xNT] ----------------
    f32x4 acc[8][4];
    #pragma unroll
    for (int i = 0; i < 8; ++i)
        #pragma unroll
        for (int j = 0; j < 4; ++j) acc[i][j] = (f32x4){0.f, 0.f, 0.f, 0.f};

    #pragma unroll
    for (int kq = 0; kq < 16; ++kq) {
        const int tap = kq >> 3, ci = kq & 7;
        const int col = ci * 32 + quad * 8;          // input-channel offset
        s16x8 bfr[4];
        #pragma unroll
        for (int nt = 0; nt < 4; ++nt)
            bfr[nt] = *(const s16x8*)&ldsx[(nt * 16 + l16 + 8 * tap) * PITCH + col];
        #pragma unroll
        for (int mt = 0; mt < 8; ++mt) {
            int m = (mt < 4 ? cb + mt * 16 : 256 + cb + (mt - 4) * 16) + l16;
            s16x8 af = *(const s16x8*)&W1[(size_t)m * 512 + kq * 32 + quad * 8];
            #pragma unroll
            for (int nt = 0; nt < 4; ++nt)
                acc[mt][nt] = __builtin_amdgcn_mfma_f32_16x16x32_bf16(af, bfr[nt], acc[mt][nt], 0, 0, 0);
        }
    }
    __syncthreads();   // all GEMM1 LDS reads done before z overwrites rows 0..63

    // ---------------- activations -> z (bf16) into LDS rows 0..63 ----------------
    #pragma unroll
    for (int mt = 0; mt < 4; ++mt) {
        const int ch0 = cb + mt * 16 + quad * 4;
        const f32x4 bf4 = *(const f32x4*)&b_filt[ch0];
        const f32x4 bg4 = *(const f32x4*)&b_gate[ch0];
        #pragma unroll
        for (int nt = 0; nt < 4; ++nt) {
            ushort zr[4];
            #pragma unroll
            for (int r = 0; r < 4; ++r) {
                float fv = acc[mt][nt][r]     + bf4[r];
                float gv = acc[mt + 4][nt][r] + bg4[r];
                zr[r] = f2b(fast_tanh(fv) * fast_sigmoid(gv));
            }
            __builtin_memcpy(&ldsx[(nt * 16 + l16) * PITCH + ch0], zr, 8);
        }
    }
    __syncthreads();

    // ---------------- GEMM2: [512x256] @ [256xNT] ----------------
    f32x4 acc2[8][4];
    #pragma unroll
    for (int i = 0; i < 8; ++i)
        #pragma unroll
        for (int j = 0; j < 4; ++j) acc2[i][j] = (f32x4){0.f, 0.f, 0.f, 0.f};

    #pragma unroll
    for (int kq = 0; kq < 8; ++kq) {
        const int col = kq * 32 + quad * 8;
        s16x8 bz[4];
        #pragma unroll
        for (int nt = 0; nt < 4; ++nt)
            bz[nt] = *(const s16x8*)&ldsx[(nt * 16 + l16) * PITCH + col];
        #pragma unroll
        for (int mt = 0; mt < 8; ++mt) {
            int m = (mt < 4 ? cb + mt * 16 : 256 + cb + (mt - 4) * 16) + l16;
            s16x8 af = *(const s16x8*)&W2[(size_t)m * 256 + col];
            #pragma unroll
            for (int nt = 0; nt < 4; ++nt)
                acc2[mt][nt] = __builtin_amdgcn_mfma_f32_16x16x32_bf16(af, bz[nt], acc2[mt][nt], 0, 0, 0);
        }
    }

    // ---------------- epilogue: out0 = x + res (f32), out1 = skip (f32) ----------------
    const size_t OUT1 = (size_t)NB * CH * TT;
    #pragma unroll
    for (int mt = 0; mt < 4; ++mt) {
        const int ch0 = cb + mt * 16 + quad * 4;
        const f32x4 br4 = *(const f32x4*)&b_res[ch0];
        const f32x4 bs4 = *(const f32x4*)&b_skip[ch0];
        #pragma unroll
        for (int nt = 0; nt < 4; ++nt) {
            const int tok = nt * 16 + l16;
            const int tg  = t0 + tok;
            #pragma unroll
            for (int r = 0; r < 4; ++r) {
                const int ch = ch0 + r;
                const size_t o = ((size_t)(b * CH + ch)) * TT + tg;
                float xv = X[(size_t)ch * TT + tg];               // exact f32 x (L2-hot)
                out[o]        = xv + acc2[mt][nt][r] + br4[r];
                out[OUT1 + o] = acc2[mt + 4][nt][r] + bs4[r];
            }
        }
    }
}

extern "C" void kernel_launch(void* const* d_in, const int* in_sizes, int n_in,
                              void* d_out, int out_size, void* d_ws, size_t ws_size,
                              hipStream_t stream) {
    const float* x   = (const float*)d_in[0];
    const float* wf  = (const float*)d_in[1];
    const float* bfi = (const float*)d_in[2];
    const float* wg  = (const float*)d_in[3];
    const float* bg  = (const float*)d_in[4];
    const float* wr  = (const float*)d_in[5];
    const float* br  = (const float*)d_in[6];
    const float* wsk = (const float*)d_in[7];
    const float* bs  = (const float*)d_in[8];

    ushort* W1 = (ushort*)d_ws;                  // 512*512 bf16
    ushort* W2 = W1 + 512 * 512;                 // 512*256 bf16

    prep_w<<<1536, 256, 0, stream>>>(wf, wg, wr, wsk, W1, W2);

    const int nBlocks = NB * (TT / NT);          // 1024
    fused_block<<<nBlocks, 256, 0, stream>>>(x, W1, W2, bfi, bg, br, bs,
                                             (float*)d_out);
}